// Round 13
// baseline (334.168 us; speedup 1.0000x reference)
//
#include <hip/hip_runtime.h>

typedef float f4 __attribute__((ext_vector_type(4)));
typedef __attribute__((ext_vector_type(4))) float f32x4;
typedef _Float16 h8 __attribute__((ext_vector_type(8)));

// LDS-only barrier: drain LDS ops, barrier, compiler fence. No vmcnt —
// all global loads are thread-private registers (compiler inserts
// data-dependent vmcnt waits at first use).
#define BAR() do { asm volatile("s_waitcnt lgkmcnt(0)" ::: "memory"); \
    __builtin_amdgcn_s_barrier(); asm volatile("" ::: "memory"); } while (0)

__global__ __launch_bounds__(256, 3)
void avif_reg(const float* __restrict__ x, const float* __restrict__ twm,
              const float* __restrict__ w1, const float* __restrict__ b1,
              const float* __restrict__ w2, const float* __restrict__ b2,
              float* __restrict__ out)
{
    // fp16 planes, XOR-swizzled on the 8-ushort (16B) granule (verified r8):
    // element (px, c) -> row px, idx = ((c>>3) ^ (px&7) ^ (((px>>3)&1)<<2))*8 + (c&7)
    __shared__ ushort ysf[128][64];   // Y fp16 (16 KB)
    __shared__ ushort hsf[128][64];   // H fp16 (16 KB) -> 32 KB total

    const int t = threadIdx.x;
    const int bid = blockIdx.x;
    // pair decode: (bid, bid+8) share (ks,hb,b), differ wc -> same XCD (bid%8),
    // adjacent launch -> co-resident -> the two 64B halves of each 128B x/out
    // line are touched in the same iteration window -> L2 merge.
    const int wc = (bid >> 3) & 1;
    const int u  = ((bid >> 4) << 3) | (bid & 7);   // 0..1023
    const int ks = u & 3;              // 4-tile segment
    const int hb = (u >> 2) & 63;
    const int b  = u >> 8;

    const int wv = t >> 6, lane = t & 63;
    const int li = lane & 15, lg = lane >> 4, l7 = li & 7;
    const int lb3 = (li >> 3) << 2;

    // ---- W fragments (fp16) + biases ----
    h8 w1f[2], w2f[2];
    {
        const float* p1 = w1 + (16 * wv + li) * 64 + lg * 8;
        const float* p2 = w2 + (16 * wv + li) * 64 + lg * 8;
#pragma unroll
        for (int kk = 0; kk < 2; ++kk) {
            f4 a = *(const f4*)(p1 + kk * 32);
            f4 d = *(const f4*)(p1 + kk * 32 + 4);
            h8 f;
#pragma unroll
            for (int q = 0; q < 4; ++q) { f[q] = (_Float16)a[q]; f[4 + q] = (_Float16)d[q]; }
            w1f[kk] = f;
            a = *(const f4*)(p2 + kk * 32);
            d = *(const f4*)(p2 + kk * 32 + 4);
#pragma unroll
            for (int q = 0; q < 4; ++q) { f[q] = (_Float16)a[q]; f[4 + q] = (_Float16)d[q]; }
            w2f[kk] = f;
        }
    }
    const int o0 = 16 * wv + 4 * lg;
    const f4 b1v = *(const f4*)(b1 + o0);
    const float b2s = b2[16 * wv + li];
    const int sg0 = ((lg       ^ l7 ^ lb3) << 3);
    const int sg1 = (((4 + lg) ^ l7 ^ lb3) << 3);
    const int go  = o0 >> 3, co = 4 * (lg & 1);
    const int ch  = 16 * wv + li;
    const int cgE = ch >> 3, c7E = li & 7;

    // ---- transform identity: lane pair shares (c,blk); h2 = col-half AND
    // q-half. Pr holds my 4 columns of P (all 8 rows); partner half via shfl.
    const int pid = t >> 1, h2 = t & 1;
    const int c   = pid & 63, blk = pid >> 6, Q0 = 4 * h2;
    const float* tB = twm + c * 64;
    const float* xb = x + ((size_t)(b * 64 + c) * 512 + hb * 8) * 512
                        + blk * 8 + 4 * h2;       // + wt*16 + i*512
    const int cg = c >> 3, c7 = c & 7;

    int wt = 2 * (ks * 4) + wc;

    // ---- prologue: load tile 0 into Pr ----
    f4 Pr[8];
#pragma unroll
    for (int i = 0; i < 8; ++i)
        Pr[i] = *(const f4*)(xb + (size_t)i * 512 + wt * 16);

#pragma unroll 1
    for (int it = 0; it < 4; ++it) {
        // ---- build M[8][4] (my 4 q-cols) from Pr + partner half via shfl ----
        float M[8][4];
        {
            f4 Tq0[4], Tq1[4];   // T[Q0+qq][my col-half] / [other half]
#pragma unroll
            for (int qq = 0; qq < 4; ++qq) {
                Tq0[qq] = *(const f4*)(tB + (Q0 + qq) * 8 + 4 * h2);
                Tq1[qq] = *(const f4*)(tB + (Q0 + qq) * 8 + 4 * (1 - h2));
            }
#pragma unroll
            for (int i = 0; i < 8; ++i) {
                f4 Px;
#pragma unroll
                for (int e = 0; e < 4; ++e) Px[e] = __shfl_xor(Pr[i][e], 1);
#pragma unroll
                for (int qq = 0; qq < 4; ++qq) {
                    float s = Pr[i][0] * Tq0[qq][0];
                    s = fmaf(Pr[i][1], Tq0[qq][1], s);
                    s = fmaf(Pr[i][2], Tq0[qq][2], s);
                    s = fmaf(Pr[i][3], Tq0[qq][3], s);
                    s = fmaf(Px[0], Tq1[qq][0], s);
                    s = fmaf(Px[1], Tq1[qq][1], s);
                    s = fmaf(Px[2], Tq1[qq][2], s);
                    s = fmaf(Px[3], Tq1[qq][3], s);
                    M[i][qq] = s;
                }
            }
        }
        // ---- Pr dead: issue next tile's loads (drain under ~whole iteration) ----
        if (it < 3) {
            const int wtn = wt + 2;
#pragma unroll
            for (int i = 0; i < 8; ++i)
                Pr[i] = *(const f4*)(xb + (size_t)i * 512 + wtn * 16);
        }
        // ---- stage 2: Y rows, my 4 q-cols; stream T rows; write ysf ----
#pragma unroll
        for (int p = 0; p < 8; ++p) {
            f4 a = *(const f4*)(tB + p * 8);
            f4 d = *(const f4*)(tB + p * 8 + 4);
            const int px0 = p * 16 + blk * 8;
#pragma unroll
            for (int qq = 0; qq < 4; ++qq) {
                const int q = Q0 + qq;
                float s = a[0] * M[0][qq];
                s = fmaf(a[1], M[1][qq], s);
                s = fmaf(a[2], M[2][qq], s);
                s = fmaf(a[3], M[3][qq], s);
                s = fmaf(d[0], M[4][qq], s);
                s = fmaf(d[1], M[5][qq], s);
                s = fmaf(d[2], M[6][qq], s);
                s = fmaf(d[3], M[7][qq], s);
                const int idx = ((cg ^ q ^ (blk << 2)) << 3) | c7;
                *(_Float16*)&ysf[px0 + q][idx] = (_Float16)s;
            }
        }
        BAR();   // B1: ysf visible

        // ---- GEMM1: H = relu(W1 * Y + b1) ----
        f32x4 acc[8];
#pragma unroll
        for (int j = 0; j < 8; ++j) acc[j] = (f32x4){0.f, 0.f, 0.f, 0.f};
#pragma unroll
        for (int j = 0; j < 8; ++j) {
            const int row = 16 * j + li;
            h8 bh0 = *(const h8*)&ysf[row][sg0];
            h8 bh1 = *(const h8*)&ysf[row][sg1];
            acc[j] = __builtin_amdgcn_mfma_f32_16x16x32_f16(w1f[0], bh0, acc[j], 0, 0, 0);
            acc[j] = __builtin_amdgcn_mfma_f32_16x16x32_f16(w1f[1], bh1, acc[j], 0, 0, 0);
        }
#pragma unroll
        for (int j = 0; j < 8; ++j) {
            const int px = 16 * j + li;
            const int idx = ((go ^ l7 ^ lb3) << 3) + co;
            union { _Float16 h[2]; unsigned u; } p01, p23;
            p01.h[0] = (_Float16)fmaxf(acc[j][0] + b1v[0], 0.f);
            p01.h[1] = (_Float16)fmaxf(acc[j][1] + b1v[1], 0.f);
            p23.h[0] = (_Float16)fmaxf(acc[j][2] + b1v[2], 0.f);
            p23.h[1] = (_Float16)fmaxf(acc[j][3] + b1v[3], 0.f);
            *(unsigned*)&hsf[px][idx]     = p01.u;
            *(unsigned*)&hsf[px][idx + 2] = p23.u;
        }
        BAR();   // B2: hsf visible

        // ---- GEMM2 swapped (A=H, B=W2): D[px][channel]; f4 stores ----
#pragma unroll
        for (int j = 0; j < 8; ++j) acc[j] = (f32x4){0.f, 0.f, 0.f, 0.f};
#pragma unroll
        for (int j = 0; j < 8; ++j) {
            const int row = 16 * j + li;
            h8 ah0 = *(const h8*)&hsf[row][sg0];
            h8 ah1 = *(const h8*)&hsf[row][sg1];
            acc[j] = __builtin_amdgcn_mfma_f32_16x16x32_f16(ah0, w2f[0], acc[j], 0, 0, 0);
            acc[j] = __builtin_amdgcn_mfma_f32_16x16x32_f16(ah1, w2f[1], acc[j], 0, 0, 0);
        }
        float* oB = out + ((size_t)(b * 64) + ch) * 262144
                    + (size_t)(hb * 8) * 512 + wt * 16 + 4 * lg;
#pragma unroll
        for (int j = 0; j < 8; ++j) {
            f4 r;
#pragma unroll
            for (int r4 = 0; r4 < 4; ++r4) {
                const int pc = 4 * lg + r4;
                const int px = 16 * j + pc;
                const int idx = ((cgE ^ (pc & 7) ^ (((pc >> 3) & 1) << 2)) << 3) | c7E;
                float yv = (float)(*(const _Float16*)&ysf[px][idx]);
                float z = acc[j][r4] + b2s;
                float g = __builtin_amdgcn_rcpf(1.f + __expf(-z));
                r[r4] = yv * g;
            }
            *(f4*)(oB + (size_t)j * 512) = r;
        }
        BAR();   // B3: ysf/hsf consumed -> next transform may overwrite

        wt += 2;
    }
}

extern "C" void kernel_launch(void* const* d_in, const int* in_sizes, int n_in,
                              void* d_out, int out_size, void* d_ws, size_t ws_size,
                              hipStream_t stream) {
    (void)in_sizes; (void)n_in; (void)out_size; (void)d_ws; (void)ws_size;
    const float* x   = (const float*)d_in[0];
    const float* twm = (const float*)d_in[1];
    const float* w1  = (const float*)d_in[2];
    const float* b1  = (const float*)d_in[3];
    const float* w2  = (const float*)d_in[4];
    const float* b2  = (const float*)d_in[5];
    float* out = (float*)d_out;

    avif_reg<<<dim3(2048), dim3(256), 0, stream>>>(x, twm, w1, b1, w2, b2, out);
}

// Round 14
// 296.822 us; speedup vs baseline: 1.1258x; 1.1258x over previous
//
#include <hip/hip_runtime.h>

typedef float f4 __attribute__((ext_vector_type(4)));
typedef __attribute__((ext_vector_type(4))) float f32x4;
typedef _Float16 h8 __attribute__((ext_vector_type(8)));
typedef _Float16 h4 __attribute__((ext_vector_type(4)));

// LDS-only barrier: all global loads are thread-private (compiler inserts
// data-dependent vmcnt); stores are never waited on.
#define BAR() do { asm volatile("s_waitcnt lgkmcnt(0)" ::: "memory"); \
    __builtin_amdgcn_s_barrier(); asm volatile("" ::: "memory"); } while (0)

__global__ __launch_bounds__(256, 2)
void avif_strip(const float* __restrict__ x, const float* __restrict__ twm,
                const float* __restrict__ w1, const float* __restrict__ b1,
                const float* __restrict__ w2, const float* __restrict__ b2,
                float* __restrict__ out)
{
    // xs: fp16 staged x for an 8row x 32col strip = two 16-col tiles.
    // ushort offset(tile, c, r, col) =
    //   tile*8192 + c*128 + ((r*2 + (col>>3)) ^ (c&15))*8 + (col&7)
    __shared__ ushort xs[2 * 64 * 128];   // 32 KB
    __shared__ ushort ysf[128][64];       // 16 KB (r8-verified swizzle)
    __shared__ ushort hsf[128][64];       // 16 KB -> 64 KB total

    const int t = threadIdx.x;
    const int bid = blockIdx.x;           // 512 = 2 sseg x 64 hb x 4 b
    const int sseg = bid & 1;
    const int hb = (bid >> 1) & 63;
    const int b  = bid >> 7;

    const int wv = t >> 6, lane = t & 63;
    const int li = lane & 15, lg = lane >> 4, l7 = li & 7;
    const int lb3 = (li >> 3) << 2;

    // ---- staging maps: granule g = j*256+t; wave inst j covers one channel's
    // full 8x128B patch (perfect coalescing). ----
    const float* xbase = x + (size_t)(b * 64) * 262144 + (size_t)hb * 8 * 512;
    int goff[16], loff[16];
#pragma unroll
    for (int j = 0; j < 16; ++j) {
        const int g = j * 256 + t;
        const int cc = g >> 6, sub = g & 63;
        const int r = sub >> 3, q8 = sub & 7;       // q8 = 16B quarter of 128B row
        goff[j] = cc * 262144 + r * 512 + q8 * 4;
        const int tile = q8 >> 2;
        const int gi = r * 2 + ((q8 & 3) >> 1);
        loff[j] = tile * 8192 + cc * 128 + ((gi ^ (cc & 15)) << 3) + (q8 & 1) * 4;
    }

    // ---- W fragments (fp16) + biases (r8/r10 verified) ----
    h8 w1f[2], w2f[2];
    {
        const float* p1 = w1 + (16 * wv + li) * 64 + lg * 8;
        const float* p2 = w2 + (16 * wv + li) * 64 + lg * 8;
#pragma unroll
        for (int kk = 0; kk < 2; ++kk) {
            f4 a = *(const f4*)(p1 + kk * 32);
            f4 d = *(const f4*)(p1 + kk * 32 + 4);
            h8 f;
#pragma unroll
            for (int q = 0; q < 4; ++q) { f[q] = (_Float16)a[q]; f[4 + q] = (_Float16)d[q]; }
            w1f[kk] = f;
            a = *(const f4*)(p2 + kk * 32);
            d = *(const f4*)(p2 + kk * 32 + 4);
#pragma unroll
            for (int q = 0; q < 4; ++q) { f[q] = (_Float16)a[q]; f[4 + q] = (_Float16)d[q]; }
            w2f[kk] = f;
        }
    }
    const int o0 = 16 * wv + 4 * lg;
    const f4 b1v = *(const f4*)(b1 + o0);
    const float b2s = b2[16 * wv + li];
    const int sg0 = ((lg       ^ l7 ^ lb3) << 3);
    const int sg1 = (((4 + lg) ^ l7 ^ lb3) << 3);
    const int go  = o0 >> 3, co = 4 * (lg & 1);
    const int ch  = 16 * wv + li;
    const int cgE = ch >> 3, c7E = li & 7;

    // ---- transform identity (lane pair shares (c,blk); q-partitioned) ----
    const int pid = t >> 1, h2 = t & 1;
    const int c   = pid & 63, blk = pid >> 6, Q0 = 4 * h2;
    const float* tB = twm + c * 64;
    const int cg = c >> 3, c7 = c & 7, cswz = c & 15;
    const int xtc = c * 128;

    f4 Pg[16];
    auto stage_load = [&](int s) {
#pragma unroll
        for (int j = 0; j < 16; ++j)
            Pg[j] = *(const f4*)(xbase + goff[j] + s * 32);
    };
    auto stage_write = [&]() {
#pragma unroll
        for (int j = 0; j < 16; ++j) {
            h4 hv;
#pragma unroll
            for (int e = 0; e < 4; ++e) hv[e] = (_Float16)Pg[j][e];
            *(h4*)&xs[loff[j]] = hv;
        }
    };

    auto transform = [&](int tile) {
        f4 Pa[8], Pd[8];
#pragma unroll
        for (int i = 0; i < 8; ++i) {
            h8 hv = *(const h8*)&xs[tile * 8192 + xtc + (((i * 2 + blk) ^ cswz) << 3)];
#pragma unroll
            for (int e = 0; e < 4; ++e) { Pa[i][e] = (float)hv[e]; Pd[i][e] = (float)hv[4 + e]; }
        }
        float M[8][4];
#pragma unroll
        for (int qq = 0; qq < 4; ++qq) {
            f4 Ta = *(const f4*)(tB + (Q0 + qq) * 8);
            f4 Td = *(const f4*)(tB + (Q0 + qq) * 8 + 4);
#pragma unroll
            for (int i = 0; i < 8; ++i) {
                float s = Pa[i][0] * Ta[0];
                s = fmaf(Pa[i][1], Ta[1], s);
                s = fmaf(Pa[i][2], Ta[2], s);
                s = fmaf(Pa[i][3], Ta[3], s);
                s = fmaf(Pd[i][0], Td[0], s);
                s = fmaf(Pd[i][1], Td[1], s);
                s = fmaf(Pd[i][2], Td[2], s);
                s = fmaf(Pd[i][3], Td[3], s);
                M[i][qq] = s;
            }
        }
#pragma unroll
        for (int p = 0; p < 8; ++p) {
            f4 a = *(const f4*)(tB + p * 8);
            f4 d = *(const f4*)(tB + p * 8 + 4);
            const int px0 = p * 16 + blk * 8;
#pragma unroll
            for (int qq = 0; qq < 4; ++qq) {
                const int q = Q0 + qq;
                float s = a[0] * M[0][qq];
                s = fmaf(a[1], M[1][qq], s);
                s = fmaf(a[2], M[2][qq], s);
                s = fmaf(a[3], M[3][qq], s);
                s = fmaf(d[0], M[4][qq], s);
                s = fmaf(d[1], M[5][qq], s);
                s = fmaf(d[2], M[6][qq], s);
                s = fmaf(d[3], M[7][qq], s);
                const int idx = ((cg ^ q ^ (blk << 2)) << 3) | c7;
                *(_Float16*)&ysf[px0 + q][idx] = (_Float16)s;
            }
        }
    };

    auto gemm1 = [&]() {
        f32x4 acc[8];
#pragma unroll
        for (int j = 0; j < 8; ++j) acc[j] = (f32x4){0.f, 0.f, 0.f, 0.f};
#pragma unroll
        for (int j = 0; j < 8; ++j) {
            const int row = 16 * j + li;
            h8 bh0 = *(const h8*)&ysf[row][sg0];
            h8 bh1 = *(const h8*)&ysf[row][sg1];
            acc[j] = __builtin_amdgcn_mfma_f32_16x16x32_f16(w1f[0], bh0, acc[j], 0, 0, 0);
            acc[j] = __builtin_amdgcn_mfma_f32_16x16x32_f16(w1f[1], bh1, acc[j], 0, 0, 0);
        }
#pragma unroll
        for (int j = 0; j < 8; ++j) {
            const int px = 16 * j + li;
            const int idx = ((go ^ l7 ^ lb3) << 3) + co;
            union { _Float16 h[2]; unsigned u; } p01, p23;
            p01.h[0] = (_Float16)fmaxf(acc[j][0] + b1v[0], 0.f);
            p01.h[1] = (_Float16)fmaxf(acc[j][1] + b1v[1], 0.f);
            p23.h[0] = (_Float16)fmaxf(acc[j][2] + b1v[2], 0.f);
            p23.h[1] = (_Float16)fmaxf(acc[j][3] + b1v[3], 0.f);
            *(unsigned*)&hsf[px][idx]     = p01.u;
            *(unsigned*)&hsf[px][idx + 2] = p23.u;
        }
    };

    auto gemm2_epi = [&](int wt) {
        f32x4 acc[8];
#pragma unroll
        for (int j = 0; j < 8; ++j) acc[j] = (f32x4){0.f, 0.f, 0.f, 0.f};
#pragma unroll
        for (int j = 0; j < 8; ++j) {
            const int row = 16 * j + li;
            h8 ah0 = *(const h8*)&hsf[row][sg0];
            h8 ah1 = *(const h8*)&hsf[row][sg1];
            acc[j] = __builtin_amdgcn_mfma_f32_16x16x32_f16(ah0, w2f[0], acc[j], 0, 0, 0);
            acc[j] = __builtin_amdgcn_mfma_f32_16x16x32_f16(ah1, w2f[1], acc[j], 0, 0, 0);
        }
        float* oB = out + ((size_t)(b * 64) + ch) * 262144
                    + (size_t)(hb * 8) * 512 + wt * 16 + 4 * lg;
#pragma unroll
        for (int j = 0; j < 8; ++j) {
            f4 r;
#pragma unroll
            for (int r4 = 0; r4 < 4; ++r4) {
                const int pc = 4 * lg + r4;
                const int px = 16 * j + pc;
                const int idx = ((cgE ^ (pc & 7) ^ (((pc >> 3) & 1) << 2)) << 3) | c7E;
                float yv = (float)(*(const _Float16*)&ysf[px][idx]);
                float z = acc[j][r4] + b2s;
                float g = __builtin_amdgcn_rcpf(1.f + __expf(-z));
                r[r4] = yv * g;
            }
            *(f4*)(oB + (size_t)j * 512) = r;
        }
    };

    // ================= prologue: stage strip s0 =================
    const int s0 = sseg * 8;
    stage_load(s0);
    stage_write();
    BAR();

#pragma unroll 1
    for (int it = 0; it < 8; ++it) {
        const int s = s0 + it;
        if (it < 7) stage_load(s + 1);    // issue at top: HBM busy all iteration

#pragma unroll
        for (int half = 0; half < 2; ++half) {
            transform(half);
            BAR();                        // ysf ready; (half==1: all xs reads done)
            if (half == 1 && it < 7) stage_write();   // write-late; xs dead
            gemm1();
            BAR();                        // hsf ready
            gemm2_epi(2 * s + half);
            BAR();                        // ysf/hsf free for next transform
        }
    }
}

extern "C" void kernel_launch(void* const* d_in, const int* in_sizes, int n_in,
                              void* d_out, int out_size, void* d_ws, size_t ws_size,
                              hipStream_t stream) {
    (void)in_sizes; (void)n_in; (void)out_size; (void)d_ws; (void)ws_size;
    const float* x   = (const float*)d_in[0];
    const float* twm = (const float*)d_in[1];
    const float* w1  = (const float*)d_in[2];
    const float* b1  = (const float*)d_in[3];
    const float* w2  = (const float*)d_in[4];
    const float* b2  = (const float*)d_in[5];
    float* out = (float*)d_out;

    avif_strip<<<dim3(512), dim3(256), 0, stream>>>(x, twm, w1, b1, w2, b2, out);
}

// Round 15
// 181.468 us; speedup vs baseline: 1.8415x; 1.6357x over previous
//
#include <hip/hip_runtime.h>

typedef float f4 __attribute__((ext_vector_type(4)));
typedef __attribute__((ext_vector_type(4))) float f32x4;
typedef _Float16 h8 __attribute__((ext_vector_type(8)));

__device__ __forceinline__ void gload_lds16(const float* g, float* l) {
    __builtin_amdgcn_global_load_lds(
        (const __attribute__((address_space(1))) void*)g,
        (__attribute__((address_space(3))) void*)l, 16, 0, 0);
}

// B_b: full drain (staging landed + lockstep glue). B_a: LDS-only (stores run free).
#define BAR_VM() do { asm volatile("s_waitcnt vmcnt(0) lgkmcnt(0)" ::: "memory"); \
    __builtin_amdgcn_s_barrier(); asm volatile("" ::: "memory"); } while (0)
#define BAR_LG() do { asm volatile("s_waitcnt lgkmcnt(0)" ::: "memory"); \
    __builtin_amdgcn_s_barrier(); asm volatile("" ::: "memory"); } while (0)

__global__ __launch_bounds__(256, 2)
void avif_pipe5(const float* __restrict__ x, const float* __restrict__ twm,
                const float* __restrict__ w1, const float* __restrict__ b1,
                const float* __restrict__ w2, const float* __restrict__ b2,
                float* __restrict__ out)
{
    // xs granule (16B) layout: (c, r, qg) -> G = c*32 + ((r*4+qg)^(c&7)),
    // staged linearly by G; XOR carried in the per-lane GLOBAL source address.
    __shared__ float xs[8192];           // 32 KB
    __shared__ ushort ysf[2][128][64];   // Y fp16, swizzled, DOUBLE-buffered (32 KB)
    __shared__ ushort hsf[128][64];      // H fp16, swizzled (16 KB)  -> 80 KB total

    const int t = threadIdx.x;
    const int bid = blockIdx.x;
    // pair-interleaved decode (r10-verified): bid and bid+256 share (b,hb),
    // differ in wc -> same XCD -> both 64B halves of each 128B line touched in
    // the same tile iteration -> L2 merge.
    const int wc  = bid >> 8;
    const int rem = bid & 255;
    const int hb  = rem & 63;
    const int b   = rem >> 6;

    const int wv = t >> 6, lane = t & 63;
    const int li = lane & 15, lg = lane >> 4, l7 = li & 7;
    const int lb3 = (li >> 3) << 2;

    // ---- persistent staging source pointers (granule j*256 + t) ----
    const float* xslab = x + (((size_t)(b * 64)) * 512 + (size_t)hb * 8) * 512 + wc * 16;
    const float* gp[8];
#pragma unroll
    for (int j = 0; j < 8; ++j) {
        const int G = j * 256 + t;
        const int c = G >> 5;
        const int v = (G & 31) ^ (c & 7);
        const int r = v >> 2, qg = v & 3;
        gp[j] = xslab + (size_t)c * 262144 + r * 512 + qg * 4;
    }
    float* lbase = &xs[wv * 256];     // wave-uniform LDS base; + j*1024 per inst

    // ---- W fragments (fp16) + biases ----
    h8 w1f[2], w2f[2];
    {
        const float* p1 = w1 + (16 * wv + li) * 64 + lg * 8;
        const float* p2 = w2 + (16 * wv + li) * 64 + lg * 8;
#pragma unroll
        for (int kk = 0; kk < 2; ++kk) {
            f4 a = *(const f4*)(p1 + kk * 32);
            f4 d = *(const f4*)(p1 + kk * 32 + 4);
            h8 f;
#pragma unroll
            for (int q = 0; q < 4; ++q) { f[q] = (_Float16)a[q]; f[4 + q] = (_Float16)d[q]; }
            w1f[kk] = f;
            a = *(const f4*)(p2 + kk * 32);
            d = *(const f4*)(p2 + kk * 32 + 4);
#pragma unroll
            for (int q = 0; q < 4; ++q) { f[q] = (_Float16)a[q]; f[4 + q] = (_Float16)d[q]; }
            w2f[kk] = f;
        }
    }
    const int o0 = 16 * wv + 4 * lg;
    const f4 b1v = *(const f4*)(b1 + o0);
    const float b2s = b2[16 * wv + li];
    const int sg0 = ((lg       ^ l7 ^ lb3) << 3);
    const int sg1 = (((4 + lg) ^ l7 ^ lb3) << 3);
    const int go  = o0 >> 3, co = 4 * (lg & 1);
    const int ch  = 16 * wv + li;
    const int cgE = ch >> 3, c7E = li & 7;

    // ---- transform identity (lane pair shares (c,blk); q-partitioned) ----
    const int pid = t >> 1, h2 = t & 1;
    const int c   = pid & 63, blk = pid >> 6, Q0 = 4 * h2;
    const float* tB = twm + c * 64;
    const int sc = c * 128, swc = c & 7;
    const int cg = c >> 3, c7 = c & 7;

    // ---- transform: xs -> M -> Y -> ysf[buf] (r10-verified math) ----
    auto transform = [&](int buf) {
        float M[8][4];
        {
            f4 Ph[8];
#pragma unroll
            for (int i = 0; i < 8; ++i)
                Ph[i] = *(const f4*)&xs[sc + ((i * 4 + blk * 2) ^ swc) * 4];
#pragma unroll
            for (int qq = 0; qq < 4; ++qq) {
                f4 Th = *(const f4*)(tB + (Q0 + qq) * 8);
#pragma unroll
                for (int i = 0; i < 8; ++i) {
                    float s = Ph[i][0] * Th[0];
                    s = fmaf(Ph[i][1], Th[1], s);
                    s = fmaf(Ph[i][2], Th[2], s);
                    s = fmaf(Ph[i][3], Th[3], s);
                    M[i][qq] = s;
                }
            }
#pragma unroll
            for (int i = 0; i < 8; ++i)
                Ph[i] = *(const f4*)&xs[sc + ((i * 4 + blk * 2 + 1) ^ swc) * 4];
#pragma unroll
            for (int qq = 0; qq < 4; ++qq) {
                f4 Th = *(const f4*)(tB + (Q0 + qq) * 8 + 4);
#pragma unroll
                for (int i = 0; i < 8; ++i) {
                    float s = M[i][qq];
                    s = fmaf(Ph[i][0], Th[0], s);
                    s = fmaf(Ph[i][1], Th[1], s);
                    s = fmaf(Ph[i][2], Th[2], s);
                    s = fmaf(Ph[i][3], Th[3], s);
                    M[i][qq] = s;
                }
            }
        }
#pragma unroll
        for (int p = 0; p < 8; ++p) {
            f4 a = *(const f4*)(tB + p * 8);
            f4 d = *(const f4*)(tB + p * 8 + 4);
            const int px0 = p * 16 + blk * 8;
#pragma unroll
            for (int qq = 0; qq < 4; ++qq) {
                const int q = Q0 + qq;
                float s = a[0] * M[0][qq];
                s = fmaf(a[1], M[1][qq], s);
                s = fmaf(a[2], M[2][qq], s);
                s = fmaf(a[3], M[3][qq], s);
                s = fmaf(d[0], M[4][qq], s);
                s = fmaf(d[1], M[5][qq], s);
                s = fmaf(d[2], M[6][qq], s);
                s = fmaf(d[3], M[7][qq], s);
                const int idx = ((cg ^ q ^ (blk << 2)) << 3) | c7;
                *(_Float16*)&ysf[buf][px0 + q][idx] = (_Float16)s;
            }
        }
    };

    // ================= prologue =================
#pragma unroll
    for (int j = 0; j < 8; ++j) gload_lds16(gp[j], lbase + j * 1024);
    BAR_VM();
    transform(0);          // T(0): xs(0) -> ysf[0]
    BAR_LG();              // B_a[-1]: ysf[0] ready; xs free

#pragma unroll 1
    for (int tile = 0; tile < 16; ++tile) {
        const int buf = tile & 1;
        const int wt  = 2 * tile + wc;

        // ---- stage(t+1): xs free (T(t) done, behind B_a) ----
        if (tile < 15) {
#pragma unroll
            for (int j = 0; j < 8; ++j)
                gload_lds16(gp[j] + (tile + 1) * 32, lbase + j * 1024);
        }

        // ---- G1(t): H = relu(W1 * Y + b1) ----
        f32x4 acc[8];
#pragma unroll
        for (int j = 0; j < 8; ++j) acc[j] = (f32x4){0.f, 0.f, 0.f, 0.f};
#pragma unroll
        for (int j = 0; j < 8; ++j) {
            const int row = 16 * j + li;
            h8 bh0 = *(const h8*)&ysf[buf][row][sg0];
            h8 bh1 = *(const h8*)&ysf[buf][row][sg1];
            acc[j] = __builtin_amdgcn_mfma_f32_16x16x32_f16(w1f[0], bh0, acc[j], 0, 0, 0);
            acc[j] = __builtin_amdgcn_mfma_f32_16x16x32_f16(w1f[1], bh1, acc[j], 0, 0, 0);
        }
#pragma unroll
        for (int j = 0; j < 8; ++j) {
            const int px = 16 * j + li;
            const int idx = ((go ^ l7 ^ lb3) << 3) + co;
            union { _Float16 h[2]; unsigned u; } p01, p23;
            p01.h[0] = (_Float16)fmaxf(acc[j][0] + b1v[0], 0.f);
            p01.h[1] = (_Float16)fmaxf(acc[j][1] + b1v[1], 0.f);
            p23.h[0] = (_Float16)fmaxf(acc[j][2] + b1v[2], 0.f);
            p23.h[1] = (_Float16)fmaxf(acc[j][3] + b1v[3], 0.f);
            *(unsigned*)&hsf[px][idx]     = p01.u;
            *(unsigned*)&hsf[px][idx + 2] = p23.u;
        }
        BAR_VM();   // B_b: hsf ready; xs(t+1) landed; lockstep glue

        // ---- G2(t) (+ epilogue)  ∥  T(t+1) -> ysf[buf^1] ----
#pragma unroll
        for (int j = 0; j < 8; ++j) acc[j] = (f32x4){0.f, 0.f, 0.f, 0.f};
#pragma unroll
        for (int j = 0; j < 8; ++j) {
            const int row = 16 * j + li;
            h8 ah0 = *(const h8*)&hsf[row][sg0];
            h8 ah1 = *(const h8*)&hsf[row][sg1];
            acc[j] = __builtin_amdgcn_mfma_f32_16x16x32_f16(ah0, w2f[0], acc[j], 0, 0, 0);
            acc[j] = __builtin_amdgcn_mfma_f32_16x16x32_f16(ah1, w2f[1], acc[j], 0, 0, 0);
        }
        float* oB = out + ((size_t)(b * 64) + ch) * 262144
                    + (size_t)(hb * 8) * 512 + wt * 16 + 4 * lg;
#pragma unroll
        for (int j = 0; j < 8; ++j) {
            f4 r;
#pragma unroll
            for (int r4 = 0; r4 < 4; ++r4) {
                const int pc = 4 * lg + r4;
                const int px = 16 * j + pc;
                const int idx = ((cgE ^ (pc & 7) ^ (((pc >> 3) & 1) << 2)) << 3) | c7E;
                float yv = (float)(*(const _Float16*)&ysf[buf][px][idx]);
                float z = acc[j][r4] + b2s;
                float g = __builtin_amdgcn_rcpf(1.f + __expf(-z));
                r[r4] = yv * g;
            }
            *(f4*)(oB + (size_t)j * 512) = r;
        }
        if (tile < 15) transform(buf ^ 1);   // T(t+1), independent of G2(t)

        if (tile < 15) BAR_LG();   // B_a: ysf[buf^1] ready; hsf consumed; stores free
    }
}

extern "C" void kernel_launch(void* const* d_in, const int* in_sizes, int n_in,
                              void* d_out, int out_size, void* d_ws, size_t ws_size,
                              hipStream_t stream) {
    (void)in_sizes; (void)n_in; (void)out_size; (void)d_ws; (void)ws_size;
    const float* x   = (const float*)d_in[0];
    const float* twm = (const float*)d_in[1];
    const float* w1  = (const float*)d_in[2];
    const float* b1  = (const float*)d_in[3];
    const float* w2  = (const float*)d_in[4];
    const float* b2  = (const float*)d_in[5];
    float* out = (float*)d_out;

    avif_pipe5<<<dim3(512), dim3(256), 0, stream>>>(x, twm, w1, b1, w2, b2, out);
}

// Round 16
// 167.047 us; speedup vs baseline: 2.0004x; 1.0863x over previous
//
#include <hip/hip_runtime.h>

typedef float f4 __attribute__((ext_vector_type(4)));
typedef __attribute__((ext_vector_type(4))) float f32x4;
typedef _Float16 h8 __attribute__((ext_vector_type(8)));

__device__ __forceinline__ void gload_lds16(const float* g, float* l) {
    __builtin_amdgcn_global_load_lds(
        (const __attribute__((address_space(1))) void*)g,
        (__attribute__((address_space(3))) void*)l, 16, 0, 0);
}

__global__ __launch_bounds__(256, 2)
void avif_pipe6(const float* __restrict__ x, const float* __restrict__ twm,
                const float* __restrict__ w1, const float* __restrict__ b1,
                const float* __restrict__ w2, const float* __restrict__ b2,
                float* __restrict__ out)
{
    // xs granule (16B) layout: (c, r, qg) -> G = c*32 + ((r*4+qg)^(c&7)),
    // staged linearly by G; XOR carried in the per-lane GLOBAL source address.
    __shared__ float xs[8192];        // 32 KB
    __shared__ ushort ysf[128][64];   // Y fp16, swizzled (16 KB)
    __shared__ ushort hsf[128][64];   // H fp16, swizzled (16 KB)
    // ts: per-channel T matrices, fp32, granule-swizzled:
    // T[c][k] at float offset c*64 + ((kg ^ (c&15))<<2) + (k&3), kg=k>>2.
    __shared__ float ts[4096];        // 16 KB -> 80 KB total (2 blocks/CU)

    const int t = threadIdx.x;
    const int bid = blockIdx.x;
    // pair-interleaved decode (r10-verified): bid and bid+256 share (b,hb),
    // differ in wc -> same XCD -> both 64B halves of each 128B x/out line
    // touched in the same tile iteration -> L2 merge.
    const int wc  = bid >> 8;
    const int rem = bid & 255;
    const int hb  = rem & 63;
    const int b   = rem >> 6;

    const int wv = t >> 6, lane = t & 63;
    const int li = lane & 15, lg = lane >> 4, l7 = li & 7;
    const int lb3 = (li >> 3) << 2;

    // ---- persistent staging source pointers (granule j*256 + t) ----
    const float* xslab = x + (((size_t)(b * 64)) * 512 + (size_t)hb * 8) * 512 + wc * 16;
    const float* gp[8];
#pragma unroll
    for (int j = 0; j < 8; ++j) {
        const int G = j * 256 + t;
        const int c = G >> 5;
        const int v = (G & 31) ^ (c & 7);
        const int r = v >> 2, qg = v & 3;
        gp[j] = xslab + (size_t)c * 262144 + r * 512 + qg * 4;
    }
    float* lbase = &xs[wv * 256];     // wave-uniform LDS base; + j*1024 per inst

    // ---- stage T matrices into LDS (once): physical slot (c,s) holds
    // logical granule kg = s ^ (c&15). ----
#pragma unroll
    for (int j = 0; j < 4; ++j) {
        const int g = j * 256 + t;    // physical granule id
        const int c = g >> 4, s = g & 15;
        const int kg = s ^ (c & 15);
        *(f4*)&ts[c * 64 + s * 4] = *(const f4*)(twm + c * 64 + kg * 4);
    }

    // ---- W fragments (fp16) + biases ----
    h8 w1f[2], w2f[2];
    {
        const float* p1 = w1 + (16 * wv + li) * 64 + lg * 8;
        const float* p2 = w2 + (16 * wv + li) * 64 + lg * 8;
#pragma unroll
        for (int kk = 0; kk < 2; ++kk) {
            f4 a = *(const f4*)(p1 + kk * 32);
            f4 d = *(const f4*)(p1 + kk * 32 + 4);
            h8 f;
#pragma unroll
            for (int q = 0; q < 4; ++q) { f[q] = (_Float16)a[q]; f[4 + q] = (_Float16)d[q]; }
            w1f[kk] = f;
            a = *(const f4*)(p2 + kk * 32);
            d = *(const f4*)(p2 + kk * 32 + 4);
#pragma unroll
            for (int q = 0; q < 4; ++q) { f[q] = (_Float16)a[q]; f[4 + q] = (_Float16)d[q]; }
            w2f[kk] = f;
        }
    }
    const int o0 = 16 * wv + 4 * lg;
    const f4 b1v = *(const f4*)(b1 + o0);
    const float b2s = b2[16 * wv + li];
    const int sg0 = ((lg       ^ l7 ^ lb3) << 3);
    const int sg1 = (((4 + lg) ^ l7 ^ lb3) << 3);
    const int go  = o0 >> 3, co = 4 * (lg & 1);
    const int ch  = 16 * wv + li;
    const int cgE = ch >> 3, c7E = li & 7;

    // ---- transform identity (lane pair shares (c,blk); q-partitioned) ----
    const int pid = t >> 1, h2 = t & 1;
    const int c   = pid & 63, blk = pid >> 6, Q0 = 4 * h2;
    const int tc  = c * 64, c15 = c & 15;    // ts base / XOR key
    const int sc = c * 128, swc = c & 7;
    const int cg = c >> 3, c7 = c & 7;

    // ================= prologue: stage tile 0 =================
#pragma unroll
    for (int j = 0; j < 8; ++j) gload_lds16(gp[j], lbase + j * 1024);
    asm volatile("s_waitcnt vmcnt(0)" ::: "memory");
    __syncthreads();

    for (int tile = 0; tile < 16; ++tile) {
        const int wt = 2 * tile + wc;

        // ---- transform: xs -> M -> Y -> ysf (fp16, swizzled); T from LDS ----
        {
            float M[8][4];
            {
                f4 Ph[8];
#pragma unroll
                for (int i = 0; i < 8; ++i)
                    Ph[i] = *(const f4*)&xs[sc + ((i * 4 + blk * 2) ^ swc) * 4];
#pragma unroll
                for (int qq = 0; qq < 4; ++qq) {
                    f4 Th = *(const f4*)&ts[tc + ((2 * (Q0 + qq)) ^ c15) * 4];
#pragma unroll
                    for (int i = 0; i < 8; ++i) {
                        float s = Ph[i][0] * Th[0];
                        s = fmaf(Ph[i][1], Th[1], s);
                        s = fmaf(Ph[i][2], Th[2], s);
                        s = fmaf(Ph[i][3], Th[3], s);
                        M[i][qq] = s;
                    }
                }
#pragma unroll
                for (int i = 0; i < 8; ++i)
                    Ph[i] = *(const f4*)&xs[sc + ((i * 4 + blk * 2 + 1) ^ swc) * 4];
#pragma unroll
                for (int qq = 0; qq < 4; ++qq) {
                    f4 Th = *(const f4*)&ts[tc + ((2 * (Q0 + qq) + 1) ^ c15) * 4];
#pragma unroll
                    for (int i = 0; i < 8; ++i) {
                        float s = M[i][qq];
                        s = fmaf(Ph[i][0], Th[0], s);
                        s = fmaf(Ph[i][1], Th[1], s);
                        s = fmaf(Ph[i][2], Th[2], s);
                        s = fmaf(Ph[i][3], Th[3], s);
                        M[i][qq] = s;
                    }
                }
            }
#pragma unroll
            for (int p = 0; p < 8; ++p) {
                f4 a = *(const f4*)&ts[tc + ((2 * p)     ^ c15) * 4];
                f4 d = *(const f4*)&ts[tc + ((2 * p + 1) ^ c15) * 4];
                const int px0 = p * 16 + blk * 8;
#pragma unroll
                for (int qq = 0; qq < 4; ++qq) {
                    const int q = Q0 + qq;
                    float s = a[0] * M[0][qq];
                    s = fmaf(a[1], M[1][qq], s);
                    s = fmaf(a[2], M[2][qq], s);
                    s = fmaf(a[3], M[3][qq], s);
                    s = fmaf(d[0], M[4][qq], s);
                    s = fmaf(d[1], M[5][qq], s);
                    s = fmaf(d[2], M[6][qq], s);
                    s = fmaf(d[3], M[7][qq], s);
                    const int idx = ((cg ^ q ^ (blk << 2)) << 3) | c7;
                    *(_Float16*)&ysf[px0 + q][idx] = (_Float16)s;
                }
            }
        }
        __syncthreads();   // B1: ysf ready, xs consumed

        // ---- issue next tile's staging (drains until just before B3) ----
        if (tile < 15) {
#pragma unroll
            for (int j = 0; j < 8; ++j)
                gload_lds16(gp[j] + (tile + 1) * 32, lbase + j * 1024);
        }

        // ---- GEMM1: H = relu(W1 * Y + b1) ----
        f32x4 acc[8];
#pragma unroll
        for (int j = 0; j < 8; ++j) acc[j] = (f32x4){0.f, 0.f, 0.f, 0.f};
#pragma unroll
        for (int j = 0; j < 8; ++j) {
            const int row = 16 * j + li;
            h8 bh0 = *(const h8*)&ysf[row][sg0];
            h8 bh1 = *(const h8*)&ysf[row][sg1];
            acc[j] = __builtin_amdgcn_mfma_f32_16x16x32_f16(w1f[0], bh0, acc[j], 0, 0, 0);
            acc[j] = __builtin_amdgcn_mfma_f32_16x16x32_f16(w1f[1], bh1, acc[j], 0, 0, 0);
        }
#pragma unroll
        for (int j = 0; j < 8; ++j) {
            const int px = 16 * j + li;
            const int idx = ((go ^ l7 ^ lb3) << 3) + co;
            union { _Float16 h[2]; unsigned u; } p01, p23;
            p01.h[0] = (_Float16)fmaxf(acc[j][0] + b1v[0], 0.f);
            p01.h[1] = (_Float16)fmaxf(acc[j][1] + b1v[1], 0.f);
            p23.h[0] = (_Float16)fmaxf(acc[j][2] + b1v[2], 0.f);
            p23.h[1] = (_Float16)fmaxf(acc[j][3] + b1v[3], 0.f);
            *(unsigned*)&hsf[px][idx]     = p01.u;
            *(unsigned*)&hsf[px][idx + 2] = p23.u;
        }
        __syncthreads();   // B2: hsf ready

        // ---- GEMM2 swapped (A=H, B=W2): D[px][channel]; epilogue f4 stores ----
#pragma unroll
        for (int j = 0; j < 8; ++j) acc[j] = (f32x4){0.f, 0.f, 0.f, 0.f};
#pragma unroll
        for (int j = 0; j < 8; ++j) {
            const int row = 16 * j + li;
            h8 ah0 = *(const h8*)&hsf[row][sg0];
            h8 ah1 = *(const h8*)&hsf[row][sg1];
            acc[j] = __builtin_amdgcn_mfma_f32_16x16x32_f16(ah0, w2f[0], acc[j], 0, 0, 0);
            acc[j] = __builtin_amdgcn_mfma_f32_16x16x32_f16(ah1, w2f[1], acc[j], 0, 0, 0);
        }
        float* oB = out + ((size_t)(b * 64) + ch) * 262144
                    + (size_t)(hb * 8) * 512 + wt * 16 + 4 * lg;
#pragma unroll
        for (int j = 0; j < 8; ++j) {
            f4 r;
#pragma unroll
            for (int r4 = 0; r4 < 4; ++r4) {
                const int pc = 4 * lg + r4;
                const int px = 16 * j + pc;
                const int idx = ((cgE ^ (pc & 7) ^ (((pc >> 3) & 1) << 2)) << 3) | c7E;
                float yv = (float)(*(const _Float16*)&ysf[px][idx]);
                float z = acc[j][r4] + b2s;
                float g = __builtin_amdgcn_rcpf(1.f + __expf(-z));
                r[r4] = yv * g;
            }
            *(f4*)(oB + (size_t)j * 512) = r;
        }
        // staging must land before next transform reads xs (after B3)
        asm volatile("s_waitcnt vmcnt(0)" ::: "memory");
        __syncthreads();   // B3: ysf/hsf consumed; xs(t+1) resident
    }
}

extern "C" void kernel_launch(void* const* d_in, const int* in_sizes, int n_in,
                              void* d_out, int out_size, void* d_ws, size_t ws_size,
                              hipStream_t stream) {
    (void)in_sizes; (void)n_in; (void)out_size; (void)d_ws; (void)ws_size;
    const float* x   = (const float*)d_in[0];
    const float* twm = (const float*)d_in[1];
    const float* w1  = (const float*)d_in[2];
    const float* b1  = (const float*)d_in[3];
    const float* w2  = (const float*)d_in[4];
    const float* b2  = (const float*)d_in[5];
    float* out = (float*)d_out;

    avif_pipe6<<<dim3(512), dim3(256), 0, stream>>>(x, twm, w1, b1, w2, b2, out);
}